// Round 1
// baseline (362.742 us; speedup 1.0000x reference)
//
#include <hip/hip_runtime.h>
#include <hip/hip_bf16.h>

#define N_ROWS 65536
#define DIM    512
#define KCLS   512
#define BUCKET 256   // padded per-class bucket for counting sort (max cnt ~170)

typedef __bf16 bf16x8 __attribute__((ext_vector_type(8)));
typedef float  f32x16 __attribute__((ext_vector_type(16)));

__device__ __forceinline__ float bf2f(ushort u) {
    union { unsigned int i; float f; } v; v.i = ((unsigned int)u) << 16; return v.f;
}

// ---------- Kernel 1: normalize -> bf16 embb + histogram + bucket scatter --
__global__ __launch_bounds__(256) void rnorm_embb_kernel(
    const float* __restrict__ emb, const int* __restrict__ labels,
    ushort* __restrict__ embb, int* __restrict__ counts,
    ushort* __restrict__ order16)
{
    const int tid  = threadIdx.x;
    const int wave = tid >> 6;
    const int lane = tid & 63;
    const int row  = blockIdx.x * 4 + wave;

    const float4* ep = (const float4*)(emb + (size_t)row * DIM + lane * 8);
    const float4 e0 = ep[0], e1 = ep[1];
    float ss = e0.x*e0.x + e0.y*e0.y + e0.z*e0.z + e0.w*e0.w
             + e1.x*e1.x + e1.y*e1.y + e1.z*e1.z + e1.w*e1.w;
    #pragma unroll
    for (int off = 1; off < 64; off <<= 1)
        ss += __shfl_xor(ss, off, 64);
    const float rn = 1.0f / fmaxf(sqrtf(ss), 1e-12f);

    bf16x8 h;
    h[0] = (__bf16)(e0.x * rn); h[1] = (__bf16)(e0.y * rn);
    h[2] = (__bf16)(e0.z * rn); h[3] = (__bf16)(e0.w * rn);
    h[4] = (__bf16)(e1.x * rn); h[5] = (__bf16)(e1.y * rn);
    h[6] = (__bf16)(e1.z * rn); h[7] = (__bf16)(e1.w * rn);
    *(bf16x8*)(embb + (size_t)row * DIM + lane * 8) = h;

    if (lane == 0) {
        const int l   = labels[row];
        const int pos = atomicAdd(&counts[l], 1);
        order16[l * BUCKET + pos] = (ushort)row;
    }
}

// ---------- Kernel 2: per-class sums & bf16 centroids ----------------------
__global__ __launch_bounds__(256) void class_sum_kernel(
    const ushort* __restrict__ embb,
    const int* __restrict__ counts, const ushort* __restrict__ order16,
    float* __restrict__ sums, ushort* __restrict__ centb)
{
    __shared__ float part[4][DIM];

    const int cls  = blockIdx.x;
    const int tid  = threadIdx.x;
    const int wave = tid >> 6;
    const int lane = tid & 63;
    const int cnt  = counts[cls];
    const int base = cls * BUCKET;
    const int d8   = lane * 8;

    float a[8] = {};
    float b2[8] = {};
    int j = wave;
    for (; j + 4 < cnt; j += 8) {       // 2 independent gather chains in flight
        const int r1 = order16[base + j];
        const int r2 = order16[base + j + 4];
        const uint4 u1 = *(const uint4*)(embb + (size_t)r1 * DIM + d8);
        const uint4 u2 = *(const uint4*)(embb + (size_t)r2 * DIM + d8);
        const ushort* s1 = (const ushort*)&u1;
        const ushort* s2 = (const ushort*)&u2;
        #pragma unroll
        for (int q = 0; q < 8; ++q) { a[q] += bf2f(s1[q]); b2[q] += bf2f(s2[q]); }
    }
    if (j < cnt) {
        const int r = order16[base + j];
        const uint4 u = *(const uint4*)(embb + (size_t)r * DIM + d8);
        const ushort* s1 = (const ushort*)&u;
        #pragma unroll
        for (int q = 0; q < 8; ++q) a[q] += bf2f(s1[q]);
    }
    #pragma unroll
    for (int q = 0; q < 8; ++q) part[wave][d8 + q] = a[q] + b2[q];
    __syncthreads();

    const int d0 = tid * 2;
    const float s0 = part[0][d0]   + part[1][d0]   + part[2][d0]   + part[3][d0];
    const float s1 = part[0][d0+1] + part[1][d0+1] + part[2][d0+1] + part[3][d0+1];
    *(float2*)(sums + (size_t)cls * DIM + d0) = make_float2(s0, s1);
    const float cinv = 1.0f / fmaxf((float)cnt, 1.0f);
    const __bf16 c0 = (__bf16)(s0 * cinv);
    const __bf16 c1 = (__bf16)(s1 * cinv);
    ushort2 cpk;
    cpk.x = *(const ushort*)&c0;
    cpk.y = *(const ushort*)&c1;
    *(ushort2*)(centb + (size_t)cls * DIM + d0) = cpk;
}

// ---------- Kernel 3: MFMA GEMM + own + logsumexp + loss + finalize --------
// Redesign: 128-row blocks, 8 waves, wave = 128 rows x 64 cols (all 512 cols
// covered in ONE K-pass -> single softmax pass). B (centb, 512 KB, L2-resident)
// is read straight from global into registers with 1-step prefetch -- no B LDS.
// A double-buffered in LDS, ONE barrier per 32-wide K-step (16 total).
#define BM    128
#define BK    32
#define A_ST  40                 // 32 k + 8 pad elems (80 B rows, 16B aligned, 4-way)
#define ABUF  (BM * A_ST)        // elems per buffer

#define MFMA_BK(AR_, B0_, B1_)                                                          \
    { const bf16x8 a0_ = *(const bf16x8*)((AR_));                                       \
      const bf16x8 a1_ = *(const bf16x8*)((AR_) + 32 * A_ST);                           \
      const bf16x8 a2_ = *(const bf16x8*)((AR_) + 64 * A_ST);                           \
      const bf16x8 a3_ = *(const bf16x8*)((AR_) + 96 * A_ST);                           \
      acc[0][0] = __builtin_amdgcn_mfma_f32_32x32x16_bf16(a0_, B0_, acc[0][0], 0,0,0);  \
      acc[1][0] = __builtin_amdgcn_mfma_f32_32x32x16_bf16(a1_, B0_, acc[1][0], 0,0,0);  \
      acc[2][0] = __builtin_amdgcn_mfma_f32_32x32x16_bf16(a2_, B0_, acc[2][0], 0,0,0);  \
      acc[3][0] = __builtin_amdgcn_mfma_f32_32x32x16_bf16(a3_, B0_, acc[3][0], 0,0,0);  \
      acc[0][1] = __builtin_amdgcn_mfma_f32_32x32x16_bf16(a0_, B1_, acc[0][1], 0,0,0);  \
      acc[1][1] = __builtin_amdgcn_mfma_f32_32x32x16_bf16(a1_, B1_, acc[1][1], 0,0,0);  \
      acc[2][1] = __builtin_amdgcn_mfma_f32_32x32x16_bf16(a2_, B1_, acc[2][1], 0,0,0);  \
      acc[3][1] = __builtin_amdgcn_mfma_f32_32x32x16_bf16(a3_, B1_, acc[3][1], 0,0,0); }

__global__ __launch_bounds__(512, 2) void fused_loss_kernel(
    const ushort* __restrict__ embb, const int* __restrict__ labels,
    const int* __restrict__ counts, const float* __restrict__ sums,
    const ushort* __restrict__ centb,
    const float* __restrict__ wp, const float* __restrict__ bp,
    float* __restrict__ loss_acc, int* __restrict__ done,
    float* __restrict__ out)
{
    __shared__ __align__(16) ushort A_lds[2 * ABUF];   // 20 KB
    __shared__ float m_ws[8][BM];
    __shared__ float s_ws[8][BM];
    __shared__ float ll_s[BM];
    __shared__ float own_s[BM];
    __shared__ int   lbl_s[BM];
    __shared__ int   rep_s[BM];

    const int tid  = threadIdx.x;
    const int wid  = tid >> 6;       // 0..7
    const int lane = tid & 63;
    const int ln31 = lane & 31;
    const int half = lane >> 5;
    const int r0   = blockIdx.x * BM;

    // ---- Phase A: leave-one-out own logit per row ----
    for (int rr = wid; rr < BM; rr += 8) {
        const int row = r0 + rr;
        const int l   = labels[row];
        const uint4 ev = *(const uint4*)(embb + (size_t)row * DIM + lane * 8);
        const ushort* eu = (const ushort*)&ev;
        const float4* sp = (const float4*)(sums + (size_t)l * DIM + lane * 8);
        const float4 s0 = sp[0], s1 = sp[1];
        const float sv[8] = {s0.x, s0.y, s0.z, s0.w, s1.x, s1.y, s1.z, s1.w};
        float d1 = 0.f, d2 = 0.f;
        #pragma unroll
        for (int jj = 0; jj < 8; ++jj) {
            const float e  = bf2f(eu[jj]);
            const float df = sv[jj] - e;
            d1 += e * df;
            d2 += df * df;
        }
        #pragma unroll
        for (int off = 32; off > 0; off >>= 1) {
            d1 += __shfl_down(d1, off, 64);
            d2 += __shfl_down(d2, off, 64);
        }
        if (lane == 0) {
            own_s[rr] = d1 / fmaxf(sqrtf(d2), 1e-12f);
            lbl_s[rr] = l;
            rep_s[rr] = (counts[l] > 1) ? 1 : 0;
        }
    }

    // ---- staging / fragment pointers ----
    const int rowS = tid >> 2;            // 0..127
    const int offS = (tid & 3) * 8;       // elem offset within the 32-wide K slab
    const ushort* aSrc = embb + (size_t)(r0 + rowS) * DIM + offS;
    ushort* aDst = A_lds + rowS * A_ST + offS;

    const int cb = wid * 64;              // this wave's 64-col panel
    const ushort* bP0 = centb + (size_t)(cb + ln31) * DIM + half * 8;   // n = 0
    const ushort* bP1 = bP0 + (size_t)32 * DIM;                          // n = 1
    const ushort* aRd = A_lds + ln31 * A_ST + half * 8;

    const float wv = fmaxf(wp[0], 1e-6f);
    const float bv = bp[0];

    f32x16 acc[4][2] = {};   // [row-frag mt][col-frag n] -- static indices only

    // ---- prologue: t = 0 ----
    uint4  aE = *(const uint4*)aSrc;
    bf16x8 bE00 = *(const bf16x8*)(bP0);
    bf16x8 bE01 = *(const bf16x8*)(bP0 + 16);
    bf16x8 bE10 = *(const bf16x8*)(bP1);
    bf16x8 bE11 = *(const bf16x8*)(bP1 + 16);
    uint4  aO;
    bf16x8 bO00, bO01, bO10, bO11;
    *(uint4*)aDst = aE;          // buf0 (waits aE only; B stays in flight)
    __syncthreads();

    // ---- K-loop: 16 steps, double-buffered A, 1 barrier per step ----
    #pragma unroll 1
    for (int d = 0; d < 8; ++d) {
        const int t0 = 2 * d;
        {   // even step: compute buf0 with E, prefetch t0+1 -> O, write buf1
            const int tn = t0 + 1;
            aO   = *(const uint4*) (aSrc + tn * BK);
            bO00 = *(const bf16x8*)(bP0 + tn * BK);
            bO01 = *(const bf16x8*)(bP0 + tn * BK + 16);
            bO10 = *(const bf16x8*)(bP1 + tn * BK);
            bO11 = *(const bf16x8*)(bP1 + tn * BK + 16);
            const ushort* ar_ = aRd;                  // buf0
            MFMA_BK(ar_,      bE00, bE10);            // ks = 0
            MFMA_BK(ar_ + 16, bE01, bE11);            // ks = 1
            *(uint4*)(aDst + ABUF) = aO;
            __syncthreads();
        }
        {   // odd step: compute buf1 with O, prefetch t0+2 -> E, write buf0
            const int tn = t0 + 2;
            if (tn < 16) {
                aE   = *(const uint4*) (aSrc + tn * BK);
                bE00 = *(const bf16x8*)(bP0 + tn * BK);
                bE01 = *(const bf16x8*)(bP0 + tn * BK + 16);
                bE10 = *(const bf16x8*)(bP1 + tn * BK);
                bE11 = *(const bf16x8*)(bP1 + tn * BK + 16);
            }
            const ushort* ar_ = aRd + ABUF;           // buf1
            MFMA_BK(ar_,      bO00, bO10);
            MFMA_BK(ar_ + 16, bO01, bO11);
            if (tn < 16) {
                *(uint4*)aDst = aE;
                __syncthreads();
            }
        }
    }

    // ---- epilogue: per-wave row max / sum-exp over its 64 cols ----
    #pragma unroll
    for (int mt = 0; mt < 4; ++mt) {
        #pragma unroll
        for (int reg = 0; reg < 16; ++reg) {
            const int row = mt * 32 + (reg & 3) + 8 * (reg >> 2) + 4 * half;
            float v0 = wv * acc[mt][0][reg] + bv;
            float v1 = wv * acc[mt][1][reg] + bv;
            const int lbl = lbl_s[row];
            const int c0  = cb + ln31;
            if (c0 == lbl) {
                if (rep_s[row]) v0 = wv * own_s[row] + bv;
                ll_s[row] = v0;
            }
            if (c0 + 32 == lbl) {
                if (rep_s[row]) v1 = wv * own_s[row] + bv;
                ll_s[row] = v1;
            }
            float mx = fmaxf(v0, v1);
            #pragma unroll
            for (int off = 1; off < 32; off <<= 1)
                mx = fmaxf(mx, __shfl_xor(mx, off, 64));
            float s = __expf(v0 - mx) + __expf(v1 - mx);
            #pragma unroll
            for (int off = 1; off < 32; off <<= 1)
                s += __shfl_xor(s, off, 64);
            if (ln31 == 0) { m_ws[wid][row] = mx; s_ws[wid][row] = s; }
        }
    }
    __syncthreads();

    // ---- final merge over 8 col-waves + loss reduction (single wave) ----
    if (tid < 64) {
        float lsum = 0.f;
        #pragma unroll
        for (int rr = tid; rr < BM; rr += 64) {
            float m = m_ws[0][rr];
            #pragma unroll
            for (int w = 1; w < 8; ++w) m = fmaxf(m, m_ws[w][rr]);
            float s = 0.f;
            #pragma unroll
            for (int w = 0; w < 8; ++w) s += s_ws[w][rr] * __expf(m_ws[w][rr] - m);
            lsum += m + __logf(s) - ll_s[rr];
        }
        #pragma unroll
        for (int off = 32; off > 0; off >>= 1)
            lsum += __shfl_down(lsum, off, 64);
        if (tid == 0) {
            atomicAdd(loss_acc, lsum);
            __threadfence();
            const int t = atomicAdd(done, 1);
            if (t == (N_ROWS / BM) - 1) {
                const float tot = atomicAdd(loss_acc, 0.0f);  // coherent read
                out[0] = tot / (float)N_ROWS;
            }
        }
    }
}

extern "C" void kernel_launch(void* const* d_in, const int* in_sizes, int n_in,
                              void* d_out, int out_size, void* d_ws, size_t ws_size,
                              hipStream_t stream)
{
    const float* emb    = (const float*)d_in[0];
    const int*   labels = (const int*)d_in[1];
    const float* wp     = (const float*)d_in[2];
    const float* bp     = (const float*)d_in[3];
    float* out = (float*)d_out;

    char* ws = (char*)d_ws;
    ushort* embb    = (ushort*)(ws + 0);              // 64 MiB
    ushort* order16 = (ushort*)(ws + 67108864);       // 512*256*2 = 256 KiB
    float*  sums    = (float*) (ws + 67371008);       // 1 MiB
    ushort* centb   = (ushort*)(ws + 68419584);       // 512 KiB
    int*    counts  = (int*)   (ws + 68943872);       // 2048 B
    float*  loss_acc= (float*) (ws + 68945920);       // 4 B
    int*    done    = (int*)   (ws + 68945924);       // 4 B

    // zero counts + loss_acc + done in one memset (contiguous 2056 B)
    hipMemsetAsync(counts, 0, 2056, stream);

    rnorm_embb_kernel<<<N_ROWS / 4, 256, 0, stream>>>(emb, labels, embb, counts, order16);
    class_sum_kernel<<<KCLS, 256, 0, stream>>>(embb, counts, order16, sums, centb);
    fused_loss_kernel<<<N_ROWS / BM, 512, 0, stream>>>(embb, labels, counts, sums,
                                                       centb, wp, bp, loss_acc, done, out);
}